// Round 9
// baseline (654.509 us; speedup 1.0000x reference)
//
#include <hip/hip_runtime.h>
#include <hip/hip_fp16.h>

#define IN_F 128
#define HEADS 4
#define OUT_F 32
#define NEG_SLOPE 0.2f

// ---------------------------------------------------------------------------
// K1: h = x @ W fused with per-node attention halves + deg zeroing.
// Register-blocked: block = 32 rows x 128 cols, thread = 4x4 tile.
// Prologue zeroes deg[32 rows] (replaces a memset dispatch; count runs after
// this kernel in stream order). Epilogue stores h as fp16 and computes
// s_src/s_dst from fp32 accumulators (segmented 8-lane shfl_xor reduce).
// ---------------------------------------------------------------------------
__global__ __launch_bounds__(256) void gemm_fused_kernel(const float* __restrict__ x,
                                                         const float* __restrict__ W,
                                                         const float* __restrict__ att_src,
                                                         const float* __restrict__ att_dst,
                                                         __half* __restrict__ h16,
                                                         float* __restrict__ s_src,
                                                         float* __restrict__ s_dst,
                                                         int* __restrict__ deg,
                                                         int n_nodes) {
    __shared__ float xs_t[128 * 36];   // [k][row], stride 36

    int tid = threadIdx.x;

    // ---- zero this block's 32 deg entries (harness poisons ws with 0xAA) ----
    if (tid < 32) {
        int n = blockIdx.x * 32 + tid;
        if (n < n_nodes) deg[n] = 0;
    }

    // ---- stage x tile (32 rows x 128 k), transposed ----
    {
        int row   = tid & 31;
        int kbase = (tid >> 5) << 4;           // 0,16,...,112
        int grow  = blockIdx.x * 32 + row;
        const float* xp = x + (size_t)grow * IN_F + kbase;
        bool ok = (grow < n_nodes);
#pragma unroll
        for (int j = 0; j < 4; ++j) {
            float4 xv = ok ? *(const float4*)(xp + j * 4)
                           : make_float4(0.f, 0.f, 0.f, 0.f);
            int k = kbase + j * 4;
            xs_t[(k + 0) * 36 + row] = xv.x;
            xs_t[(k + 1) * 36 + row] = xv.y;
            xs_t[(k + 2) * 36 + row] = xv.z;
            xs_t[(k + 3) * 36 + row] = xv.w;
        }
    }
    __syncthreads();

    // ---- compute 4 rows x 4 cols per thread ----
    int c4 = (tid & 31) << 2;
    int r4 = (tid >> 5) << 2;

    float4 acc0 = make_float4(0.f, 0.f, 0.f, 0.f);
    float4 acc1 = make_float4(0.f, 0.f, 0.f, 0.f);
    float4 acc2 = make_float4(0.f, 0.f, 0.f, 0.f);
    float4 acc3 = make_float4(0.f, 0.f, 0.f, 0.f);

#pragma unroll 8
    for (int k = 0; k < 128; ++k) {
        float4 xv = *(const float4*)(xs_t + k * 36 + r4);
        float4 wv = *(const float4*)(W + k * IN_F + c4);
        acc0.x += xv.x * wv.x; acc0.y += xv.x * wv.y; acc0.z += xv.x * wv.z; acc0.w += xv.x * wv.w;
        acc1.x += xv.y * wv.x; acc1.y += xv.y * wv.y; acc1.z += xv.y * wv.z; acc1.w += xv.y * wv.w;
        acc2.x += xv.z * wv.x; acc2.y += xv.z * wv.y; acc2.z += xv.z * wv.z; acc2.w += xv.z * wv.w;
        acc3.x += xv.w * wv.x; acc3.y += xv.w * wv.y; acc3.z += xv.w * wv.z; acc3.w += xv.w * wv.w;
    }

    int grow = blockIdx.x * 32 + r4;

    // ---- store h as fp16 ----
#pragma unroll
    for (int r = 0; r < 4; ++r) {
        float4 a = (r == 0) ? acc0 : (r == 1) ? acc1 : (r == 2) ? acc2 : acc3;
        if (grow + r < n_nodes) {
            __half2 pa = __floats2half2_rn(a.x, a.y);
            __half2 pb = __floats2half2_rn(a.z, a.w);
            __half* hp = h16 + (((unsigned)(grow + r)) << 7) + c4;
            *(__half2*)(hp + 0) = pa;
            *(__half2*)(hp + 2) = pb;
        }
    }

    // ---- fused attention halves (full fp32 precision) ----
    int hh = c4 >> 5;          // head of this thread's 4 cols
    int cw = c4 & 31;          // within-head col
    float4 asv = *(const float4*)(att_src + (hh << 5) + cw);
    float4 adv = *(const float4*)(att_dst + (hh << 5) + cw);

    float ps0 = acc0.x*asv.x + acc0.y*asv.y + acc0.z*asv.z + acc0.w*asv.w;
    float ps1 = acc1.x*asv.x + acc1.y*asv.y + acc1.z*asv.z + acc1.w*asv.w;
    float ps2 = acc2.x*asv.x + acc2.y*asv.y + acc2.z*asv.z + acc2.w*asv.w;
    float ps3 = acc3.x*asv.x + acc3.y*asv.y + acc3.z*asv.z + acc3.w*asv.w;
    float pd0 = acc0.x*adv.x + acc0.y*adv.y + acc0.z*adv.z + acc0.w*adv.w;
    float pd1 = acc1.x*adv.x + acc1.y*adv.y + acc1.z*adv.z + acc1.w*adv.w;
    float pd2 = acc2.x*adv.x + acc2.y*adv.y + acc2.z*adv.z + acc2.w*adv.w;
    float pd3 = acc3.x*adv.x + acc3.y*adv.y + acc3.z*adv.z + acc3.w*adv.w;

    // segmented reduce over the 8 lanes sharing (row-quad, head)
#pragma unroll
    for (int m = 1; m <= 4; m <<= 1) {
        ps0 += __shfl_xor(ps0, m); pd0 += __shfl_xor(pd0, m);
        ps1 += __shfl_xor(ps1, m); pd1 += __shfl_xor(pd1, m);
        ps2 += __shfl_xor(ps2, m); pd2 += __shfl_xor(pd2, m);
        ps3 += __shfl_xor(ps3, m); pd3 += __shfl_xor(pd3, m);
    }

    if ((tid & 7) == 0) {
#pragma unroll
        for (int r = 0; r < 4; ++r) {
            float ps = (r == 0) ? ps0 : (r == 1) ? ps1 : (r == 2) ? ps2 : ps3;
            float pd = (r == 0) ? pd0 : (r == 1) ? pd1 : (r == 2) ? pd2 : pd3;
            int n = grow + r;
            if (n < n_nodes) {
                s_src[((unsigned)n << 2) + hh] = ps;
                s_dst[((unsigned)n << 2) + hh] = pd;
            }
        }
    }
}

// ---------------------------------------------------------------------------
// K2: per-dst-degree histogram
// ---------------------------------------------------------------------------
__global__ __launch_bounds__(256) void count_kernel(const int* __restrict__ ei,
                                                    int* __restrict__ deg, int E) {
    int e = blockIdx.x * 256 + threadIdx.x;
    if (e < E) atomicAdd(&deg[ei[E + e]], 1);
}

// ---------------------------------------------------------------------------
// K3: single-block exclusive scan (replaces 3-dispatch scan cascade).
// 1024 threads; thread t owns a contiguous chunk of ~98 elements.
// Produces rowptr[0..N] and cursor (deg[i] := rowptr[i]).
// ---------------------------------------------------------------------------
__global__ __launch_bounds__(1024) void scan_kernel(int* __restrict__ deg,
                                                    int* __restrict__ rowptr, int N) {
    __shared__ int s[1024];
    int t = threadIdx.x;
    const int CH = (N + 1023) / 1024;
    int lo = t * CH, hi = lo + CH; if (hi > N) hi = N;

    int sum = 0;
    for (int i = lo; i < hi; ++i) sum += deg[i];
    s[t] = sum;
    __syncthreads();
    // Hillis-Steele inclusive scan over 1024 partials
    for (int off = 1; off < 1024; off <<= 1) {
        int add = (t >= off) ? s[t - off] : 0;
        __syncthreads();
        s[t] += add;
        __syncthreads();
    }
    int run = t ? s[t - 1] : 0;     // exclusive prefix of this chunk
    for (int i = lo; i < hi; ++i) {
        int d = deg[i];
        rowptr[i] = run;
        deg[i]    = run;            // reuse deg as the scatter cursor
        run += d;
    }
    if (t == 1023) rowptr[N] = s[1023];
}

// ---------------------------------------------------------------------------
// K4: scatter src ids AND per-edge softmax numerators exp(leaky(e)) per head.
// ---------------------------------------------------------------------------
__global__ __launch_bounds__(256) void fill_kernel(const int* __restrict__ ei,
                                                   int* __restrict__ cursor,
                                                   const float* __restrict__ s_src,
                                                   const float* __restrict__ s_dst,
                                                   int* __restrict__ esrc,
                                                   float4* __restrict__ pexp, int E) {
    int e = blockIdx.x * 256 + threadIdx.x;
    if (e >= E) return;
    int s = ei[e], d = ei[E + e];
    int pos = atomicAdd(&cursor[d], 1);
    esrc[pos] = s;

    float4 as = *(const float4*)(s_src + ((size_t)s << 2));
    float4 ad = *(const float4*)(s_dst + ((size_t)d << 2));
    float v0 = as.x + ad.x, v1 = as.y + ad.y, v2 = as.z + ad.z, v3 = as.w + ad.w;
    v0 = v0 > 0.f ? v0 : NEG_SLOPE * v0;
    v1 = v1 > 0.f ? v1 : NEG_SLOPE * v1;
    v2 = v2 > 0.f ? v2 : NEG_SLOPE * v2;
    v3 = v3 > 0.f ? v3 : NEG_SLOPE * v3;
    float4 p; p.x = expf(v0); p.y = expf(v1); p.z = expf(v2); p.w = expf(v3);
    pexp[pos] = p;
}

// ---------------------------------------------------------------------------
// K5: gather-reduce aggregate. PERSISTENT grid-stride waves: 8192 waves, each
// handles ~N/8192 nodes -> per-wave work evens out (fixes Poisson-degree
// imbalance of wave-per-node). Lane owns 2 features; fp16 h gather.
// ---------------------------------------------------------------------------
#define AGG_BLOCKS 2048
__global__ __launch_bounds__(256) void aggregate_kernel(const int* __restrict__ rowptr,
                                                        const int* __restrict__ esrc,
                                                        const float4* __restrict__ pexp,
                                                        const __half* __restrict__ h16,
                                                        const float* __restrict__ s_src,
                                                        const float* __restrict__ s_dst,
                                                        const float* __restrict__ bias,
                                                        float* __restrict__ out,
                                                        int N) {
    int lane = threadIdx.x & 63;
    int gw   = blockIdx.x * 4 + (threadIdx.x >> 6);   // global wave id
    const int NW = AGG_BLOCKS * 4;

    unsigned f  = (unsigned)lane * 2u;     // this lane's 2 features
    int      hh = lane >> 4;               // head

    const float* pexp_f = (const float*)pexp;
    float bx = bias[f], by = bias[f + 1];  // node-invariant

    for (int n = gw; n < N; n += NW) {
        // self-loop message
        float e0 = s_src[((unsigned)n << 2) + hh] + s_dst[((unsigned)n << 2) + hh];
        e0 = e0 > 0.f ? e0 : NEG_SLOPE * e0;
        float p0 = expf(e0);
        float2 hv = __half22float2(*(const __half2*)(h16 + (((unsigned)n << 7) | f)));
        float accx = p0 * hv.x, accy = p0 * hv.y, den = p0;

        int k0 = rowptr[n], k1 = rowptr[n + 1];
        for (int base = k0; base < k1; base += 64) {
            int cnt = k1 - base; if (cnt > 64) cnt = 64;
            int msrc = (lane < cnt) ? esrc[base + lane] : 0;
#pragma unroll 8
            for (int j = 0; j < cnt; ++j) {
                int src = __builtin_amdgcn_readlane(msrc, j);   // j wave-uniform -> SGPR
                float pp = pexp_f[(((unsigned)(base + j)) << 2) | (unsigned)hh];
                float2 hs = __half22float2(*(const __half2*)(h16 + (((unsigned)src << 7) | f)));
                accx += pp * hs.x;
                accy += pp * hs.y;
                den  += pp;
            }
        }

        float inv = 1.f / (den + 1e-16f);
        float2 o;
        o.x = accx * inv + bx;
        o.y = accy * inv + by;
        *(float2*)(out + (((unsigned)n << 7) | f)) = o;
    }
}

// ---------------------------------------------------------------------------
extern "C" void kernel_launch(void* const* d_in, const int* in_sizes, int n_in,
                              void* d_out, int out_size, void* d_ws, size_t ws_size,
                              hipStream_t stream) {
    const float* x       = (const float*)d_in[0];
    const int*   ei      = (const int*)d_in[1];   // harness stages integers as int32
    const float* W       = (const float*)d_in[2];
    const float* att_src = (const float*)d_in[3];
    const float* att_dst = (const float*)d_in[4];
    const float* bias    = (const float*)d_in[5];
    float*       out     = (float*)d_out;

    const int N = in_sizes[0] / IN_F;   // 100000
    const int E = in_sizes[1] / 2;      // 1600000

    // workspace layout (~61 MB): pexp first for 16-B alignment
    char*   wsp    = (char*)d_ws;
    float4* pexp   = (float4*)wsp;                    wsp += (size_t)E * 16;
    __half* h16    = (__half*)wsp;                    wsp += (size_t)N * IN_F * 2;
    float*  s_src  = (float*)wsp;                     wsp += (size_t)N * HEADS * 4;
    float*  s_dst  = (float*)wsp;                     wsp += (size_t)N * HEADS * 4;
    int*    esrc   = (int*)wsp;                       wsp += (size_t)E * 4;
    int*    deg    = (int*)wsp;                       wsp += (size_t)N * 4;
    int*    rowptr = (int*)wsp;

    // 5 dispatches total (was 9): gemm(+zero), count, scan, fill, aggregate
    gemm_fused_kernel<<<(N + 31) / 32, 256, 0, stream>>>(x, W, att_src, att_dst,
                                                         h16, s_src, s_dst, deg, N);
    count_kernel<<<(E + 255) / 256, 256, 0, stream>>>(ei, deg, E);
    scan_kernel<<<1, 1024, 0, stream>>>(deg, rowptr, N);
    fill_kernel<<<(E + 255) / 256, 256, 0, stream>>>(ei, deg, s_src, s_dst, esrc, pexp, E);
    aggregate_kernel<<<AGG_BLOCKS, 256, 0, stream>>>(rowptr, esrc, pexp, h16,
                                                     s_src, s_dst, bias, out, N);
}

// Round 12
// 450.051 us; speedup vs baseline: 1.4543x; 1.4543x over previous
//
#include <hip/hip_runtime.h>
#include <hip/hip_fp16.h>

#define IN_F 128
#define HEADS 4
#define OUT_F 32
#define NEG_SLOPE 0.2f

// ---------------------------------------------------------------------------
// K1: h = x @ W fused with per-node attention halves + deg zeroing.
// Register-blocked: block = 32 rows x 128 cols, thread = 4x4 tile.
// ---------------------------------------------------------------------------
__global__ __launch_bounds__(256) void gemm_fused_kernel(const float* __restrict__ x,
                                                         const float* __restrict__ W,
                                                         const float* __restrict__ att_src,
                                                         const float* __restrict__ att_dst,
                                                         __half* __restrict__ h16,
                                                         float* __restrict__ s_src,
                                                         float* __restrict__ s_dst,
                                                         int* __restrict__ deg,
                                                         int n_nodes) {
    __shared__ float xs_t[128 * 36];   // [k][row], stride 36

    int tid = threadIdx.x;

    // ---- zero this block's 32 deg entries (ws is poisoned 0xAA) ----
    if (tid < 32) {
        int n = blockIdx.x * 32 + tid;
        if (n < n_nodes) deg[n] = 0;
    }

    // ---- stage x tile (32 rows x 128 k), transposed ----
    {
        int row   = tid & 31;
        int kbase = (tid >> 5) << 4;           // 0,16,...,112
        int grow  = blockIdx.x * 32 + row;
        const float* xp = x + (size_t)grow * IN_F + kbase;
        bool ok = (grow < n_nodes);
#pragma unroll
        for (int j = 0; j < 4; ++j) {
            float4 xv = ok ? *(const float4*)(xp + j * 4)
                           : make_float4(0.f, 0.f, 0.f, 0.f);
            int k = kbase + j * 4;
            xs_t[(k + 0) * 36 + row] = xv.x;
            xs_t[(k + 1) * 36 + row] = xv.y;
            xs_t[(k + 2) * 36 + row] = xv.z;
            xs_t[(k + 3) * 36 + row] = xv.w;
        }
    }
    __syncthreads();

    // ---- compute 4 rows x 4 cols per thread ----
    int c4 = (tid & 31) << 2;
    int r4 = (tid >> 5) << 2;

    float4 acc0 = make_float4(0.f, 0.f, 0.f, 0.f);
    float4 acc1 = make_float4(0.f, 0.f, 0.f, 0.f);
    float4 acc2 = make_float4(0.f, 0.f, 0.f, 0.f);
    float4 acc3 = make_float4(0.f, 0.f, 0.f, 0.f);

#pragma unroll 8
    for (int k = 0; k < 128; ++k) {
        float4 xv = *(const float4*)(xs_t + k * 36 + r4);
        float4 wv = *(const float4*)(W + k * IN_F + c4);
        acc0.x += xv.x * wv.x; acc0.y += xv.x * wv.y; acc0.z += xv.x * wv.z; acc0.w += xv.x * wv.w;
        acc1.x += xv.y * wv.x; acc1.y += xv.y * wv.y; acc1.z += xv.y * wv.z; acc1.w += xv.y * wv.w;
        acc2.x += xv.z * wv.x; acc2.y += xv.z * wv.y; acc2.z += xv.z * wv.z; acc2.w += xv.z * wv.w;
        acc3.x += xv.w * wv.x; acc3.y += xv.w * wv.y; acc3.z += xv.w * wv.z; acc3.w += xv.w * wv.w;
    }

    int grow = blockIdx.x * 32 + r4;

    // ---- store h as fp16 ----
#pragma unroll
    for (int r = 0; r < 4; ++r) {
        float4 a = (r == 0) ? acc0 : (r == 1) ? acc1 : (r == 2) ? acc2 : acc3;
        if (grow + r < n_nodes) {
            __half2 pa = __floats2half2_rn(a.x, a.y);
            __half2 pb = __floats2half2_rn(a.z, a.w);
            __half* hp = h16 + (((unsigned)(grow + r)) << 7) + c4;
            *(__half2*)(hp + 0) = pa;
            *(__half2*)(hp + 2) = pb;
        }
    }

    // ---- fused attention halves (full fp32 precision) ----
    int hh = c4 >> 5;          // head of this thread's 4 cols
    int cw = c4 & 31;          // within-head col
    float4 asv = *(const float4*)(att_src + (hh << 5) + cw);
    float4 adv = *(const float4*)(att_dst + (hh << 5) + cw);

    float ps0 = acc0.x*asv.x + acc0.y*asv.y + acc0.z*asv.z + acc0.w*asv.w;
    float ps1 = acc1.x*asv.x + acc1.y*asv.y + acc1.z*asv.z + acc1.w*asv.w;
    float ps2 = acc2.x*asv.x + acc2.y*asv.y + acc2.z*asv.z + acc2.w*asv.w;
    float ps3 = acc3.x*asv.x + acc3.y*asv.y + acc3.z*asv.z + acc3.w*asv.w;
    float pd0 = acc0.x*adv.x + acc0.y*adv.y + acc0.z*adv.z + acc0.w*adv.w;
    float pd1 = acc1.x*adv.x + acc1.y*adv.y + acc1.z*adv.z + acc1.w*adv.w;
    float pd2 = acc2.x*adv.x + acc2.y*adv.y + acc2.z*adv.z + acc2.w*adv.w;
    float pd3 = acc3.x*adv.x + acc3.y*adv.y + acc3.z*adv.z + acc3.w*adv.w;

    // segmented reduce over the 8 lanes sharing (row-quad, head)
#pragma unroll
    for (int m = 1; m <= 4; m <<= 1) {
        ps0 += __shfl_xor(ps0, m); pd0 += __shfl_xor(pd0, m);
        ps1 += __shfl_xor(ps1, m); pd1 += __shfl_xor(pd1, m);
        ps2 += __shfl_xor(ps2, m); pd2 += __shfl_xor(pd2, m);
        ps3 += __shfl_xor(ps3, m); pd3 += __shfl_xor(pd3, m);
    }

    if ((tid & 7) == 0) {
#pragma unroll
        for (int r = 0; r < 4; ++r) {
            float ps = (r == 0) ? ps0 : (r == 1) ? ps1 : (r == 2) ? ps2 : ps3;
            float pd = (r == 0) ? pd0 : (r == 1) ? pd1 : (r == 2) ? pd2 : pd3;
            int n = grow + r;
            if (n < n_nodes) {
                s_src[((unsigned)n << 2) + hh] = ps;
                s_dst[((unsigned)n << 2) + hh] = pd;
            }
        }
    }
}

// ---------------------------------------------------------------------------
// K2: per-dst-degree histogram
// ---------------------------------------------------------------------------
__global__ __launch_bounds__(256) void count_kernel(const int* __restrict__ ei,
                                                    int* __restrict__ deg, int E) {
    int e = blockIdx.x * 256 + threadIdx.x;
    if (e < E) atomicAdd(&deg[ei[E + e]], 1);
}

// ---------------------------------------------------------------------------
// 3-phase exclusive scan cascade (multi-block, each dispatch ~5-10us).
// ---------------------------------------------------------------------------
__global__ __launch_bounds__(256) void scan1_kernel(const int* __restrict__ deg,
                                                    int* __restrict__ blksum, int N) {
    __shared__ int s[256];
    int base = blockIdx.x * 1024 + threadIdx.x * 4;
    int sum = 0;
#pragma unroll
    for (int j = 0; j < 4; ++j) { int i = base + j; if (i < N) sum += deg[i]; }
    s[threadIdx.x] = sum;
    __syncthreads();
    for (int off = 128; off > 0; off >>= 1) {
        if (threadIdx.x < off) s[threadIdx.x] += s[threadIdx.x + off];
        __syncthreads();
    }
    if (threadIdx.x == 0) blksum[blockIdx.x] = s[0];
}

__global__ __launch_bounds__(256) void scan2_kernel(const int* __restrict__ blksum,
                                                    int* __restrict__ blkoff, int nblk) {
    __shared__ int s[256];
    int t = threadIdx.x;
    int v = (t < nblk) ? blksum[t] : 0;
    s[t] = v;
    __syncthreads();
    for (int off = 1; off < 256; off <<= 1) {
        int add = (t >= off) ? s[t - off] : 0;
        __syncthreads();
        s[t] += add;
        __syncthreads();
    }
    if (t < nblk) blkoff[t] = s[t] - v;   // exclusive
}

__global__ __launch_bounds__(256) void scan3_kernel(int* __restrict__ deg,
                                                    const int* __restrict__ blkoff,
                                                    int* __restrict__ rowptr, int N) {
    __shared__ int s[256];
    int t = threadIdx.x;
    int base = blockIdx.x * 1024 + t * 4;
    int d[4];
    int loc = 0;
#pragma unroll
    for (int j = 0; j < 4; ++j) { int i = base + j; d[j] = (i < N) ? deg[i] : 0; loc += d[j]; }
    s[t] = loc;
    __syncthreads();
    for (int off = 1; off < 256; off <<= 1) {
        int add = (t >= off) ? s[t - off] : 0;
        __syncthreads();
        s[t] += add;
        __syncthreads();
    }
    int run = s[t] - loc + blkoff[blockIdx.x];
#pragma unroll
    for (int j = 0; j < 4; ++j) {
        int i = base + j;
        if (i < N) {
            rowptr[i] = run;
            deg[i]    = run;        // reuse deg as the scatter cursor
            run += d[j];
            if (i == N - 1) rowptr[N] = run;
        }
    }
}

// ---------------------------------------------------------------------------
// K4: scatter src ids AND per-edge softmax numerators exp(leaky(e)) per head.
// ---------------------------------------------------------------------------
__global__ __launch_bounds__(256) void fill_kernel(const int* __restrict__ ei,
                                                   int* __restrict__ cursor,
                                                   const float* __restrict__ s_src,
                                                   const float* __restrict__ s_dst,
                                                   int* __restrict__ esrc,
                                                   float4* __restrict__ pexp, int E) {
    int e = blockIdx.x * 256 + threadIdx.x;
    if (e >= E) return;
    int s = ei[e], d = ei[E + e];
    int pos = atomicAdd(&cursor[d], 1);
    esrc[pos] = s;

    float4 as = *(const float4*)(s_src + ((size_t)s << 2));
    float4 ad = *(const float4*)(s_dst + ((size_t)d << 2));
    float v0 = as.x + ad.x, v1 = as.y + ad.y, v2 = as.z + ad.z, v3 = as.w + ad.w;
    v0 = v0 > 0.f ? v0 : NEG_SLOPE * v0;
    v1 = v1 > 0.f ? v1 : NEG_SLOPE * v1;
    v2 = v2 > 0.f ? v2 : NEG_SLOPE * v2;
    v3 = v3 > 0.f ? v3 : NEG_SLOPE * v3;
    float4 p; p.x = expf(v0); p.y = expf(v1); p.z = expf(v2); p.w = expf(v3);
    pexp[pos] = p;
}

// ---------------------------------------------------------------------------
// K5: gather-reduce aggregate. Persistent grid-stride waves (8192 waves,
// ~12 nodes each) to even out Poisson-degree imbalance. fp16 h gather.
// ---------------------------------------------------------------------------
#define AGG_BLOCKS 2048
__global__ __launch_bounds__(256) void aggregate_kernel(const int* __restrict__ rowptr,
                                                        const int* __restrict__ esrc,
                                                        const float4* __restrict__ pexp,
                                                        const __half* __restrict__ h16,
                                                        const float* __restrict__ s_src,
                                                        const float* __restrict__ s_dst,
                                                        const float* __restrict__ bias,
                                                        float* __restrict__ out,
                                                        int N) {
    int lane = threadIdx.x & 63;
    int gw   = blockIdx.x * 4 + (threadIdx.x >> 6);   // global wave id
    const int NW = AGG_BLOCKS * 4;

    unsigned f  = (unsigned)lane * 2u;     // this lane's 2 features
    int      hh = lane >> 4;               // head

    const float* pexp_f = (const float*)pexp;
    float bx = bias[f], by = bias[f + 1];  // node-invariant

    for (int n = gw; n < N; n += NW) {
        // self-loop message
        float e0 = s_src[((unsigned)n << 2) + hh] + s_dst[((unsigned)n << 2) + hh];
        e0 = e0 > 0.f ? e0 : NEG_SLOPE * e0;
        float p0 = expf(e0);
        float2 hv = __half22float2(*(const __half2*)(h16 + (((unsigned)n << 7) | f)));
        float accx = p0 * hv.x, accy = p0 * hv.y, den = p0;

        int k0 = rowptr[n], k1 = rowptr[n + 1];
        for (int base = k0; base < k1; base += 64) {
            int cnt = k1 - base; if (cnt > 64) cnt = 64;
            int msrc = (lane < cnt) ? esrc[base + lane] : 0;
#pragma unroll 8
            for (int j = 0; j < cnt; ++j) {
                int src = __builtin_amdgcn_readlane(msrc, j);   // j wave-uniform -> SGPR
                float pp = pexp_f[(((unsigned)(base + j)) << 2) | (unsigned)hh];
                float2 hs = __half22float2(*(const __half2*)(h16 + (((unsigned)src << 7) | f)));
                accx += pp * hs.x;
                accy += pp * hs.y;
                den  += pp;
            }
        }

        float inv = 1.f / (den + 1e-16f);
        float2 o;
        o.x = accx * inv + bx;
        o.y = accy * inv + by;
        *(float2*)(out + (((unsigned)n << 7) | f)) = o;
    }
}

// ---------------------------------------------------------------------------
extern "C" void kernel_launch(void* const* d_in, const int* in_sizes, int n_in,
                              void* d_out, int out_size, void* d_ws, size_t ws_size,
                              hipStream_t stream) {
    const float* x       = (const float*)d_in[0];
    const int*   ei      = (const int*)d_in[1];   // harness stages integers as int32
    const float* W       = (const float*)d_in[2];
    const float* att_src = (const float*)d_in[3];
    const float* att_dst = (const float*)d_in[4];
    const float* bias    = (const float*)d_in[5];
    float*       out     = (float*)d_out;

    const int N = in_sizes[0] / IN_F;   // 100000
    const int E = in_sizes[1] / 2;      // 1600000

    // workspace layout (~61 MB): pexp first for 16-B alignment
    char*   wsp    = (char*)d_ws;
    float4* pexp   = (float4*)wsp;                    wsp += (size_t)E * 16;
    __half* h16    = (__half*)wsp;                    wsp += (size_t)N * IN_F * 2;
    float*  s_src  = (float*)wsp;                     wsp += (size_t)N * HEADS * 4;
    float*  s_dst  = (float*)wsp;                     wsp += (size_t)N * HEADS * 4;
    int*    esrc   = (int*)wsp;                       wsp += (size_t)E * 4;
    int*    deg    = (int*)wsp;                       wsp += (size_t)N * 4;
    int*    rowptr = (int*)wsp;                       wsp += (size_t)(N + 1) * 4;
    int*    blksum = (int*)wsp;                       wsp += 256 * 4;
    int*    blkoff = (int*)wsp;

    const int nblk_scan = (N + 1023) / 1024;          // 98 <= 256

    // 7 dispatches: gemm(+zero), count, scan1, scan2, scan3, fill, aggregate
    gemm_fused_kernel<<<(N + 31) / 32, 256, 0, stream>>>(x, W, att_src, att_dst,
                                                         h16, s_src, s_dst, deg, N);
    count_kernel<<<(E + 255) / 256, 256, 0, stream>>>(ei, deg, E);
    scan1_kernel<<<nblk_scan, 256, 0, stream>>>(deg, blksum, N);
    scan2_kernel<<<1, 256, 0, stream>>>(blksum, blkoff, nblk_scan);
    scan3_kernel<<<nblk_scan, 256, 0, stream>>>(deg, blkoff, rowptr, N);
    fill_kernel<<<(E + 255) / 256, 256, 0, stream>>>(ei, deg, s_src, s_dst, esrc, pexp, E);
    aggregate_kernel<<<AGG_BLOCKS, 256, 0, stream>>>(rowptr, esrc, pexp, h16,
                                                     s_src, s_dst, bias, out, N);
}

// Round 14
// 441.198 us; speedup vs baseline: 1.4835x; 1.0201x over previous
//
#include <hip/hip_runtime.h>
#include <hip/hip_fp16.h>

#define IN_F 128
#define HEADS 4
#define OUT_F 32
#define NEG_SLOPE 0.2f

// ---------------------------------------------------------------------------
// K1: h = x @ W fused with attention halves + dst-degree histogram.
// Register-blocked: block = 32 rows x 128 cols, thread = 4x4 tile.
// Prologue: grid-stride count of edge destinations (hides under VALU-bound
// GEMM; deg pre-zeroed by memset so no zero/count race across blocks).
// Epilogue: h stored fp16; s_src/s_dst from fp32 accs (8-lane shfl reduce).
// ---------------------------------------------------------------------------
__global__ __launch_bounds__(256) void gemm_fused_kernel(const float* __restrict__ x,
                                                         const float* __restrict__ W,
                                                         const float* __restrict__ att_src,
                                                         const float* __restrict__ att_dst,
                                                         const int* __restrict__ ei_dst,
                                                         __half* __restrict__ h16,
                                                         float* __restrict__ s_src,
                                                         float* __restrict__ s_dst,
                                                         int* __restrict__ deg,
                                                         int n_nodes, int E) {
    __shared__ float xs_t[128 * 36];   // [k][row], stride 36

    int tid = threadIdx.x;

    // ---- fused dst histogram (fire-and-forget atomics, ~2 edges/thread) ----
    {
        int gid = blockIdx.x * 256 + tid;
        int nt  = gridDim.x << 8;
        for (int e = gid; e < E; e += nt)
            atomicAdd(&deg[ei_dst[e]], 1);
    }

    // ---- stage x tile (32 rows x 128 k), transposed ----
    {
        int row   = tid & 31;
        int kbase = (tid >> 5) << 4;           // 0,16,...,112
        int grow  = blockIdx.x * 32 + row;
        const float* xp = x + (size_t)grow * IN_F + kbase;
        bool ok = (grow < n_nodes);
#pragma unroll
        for (int j = 0; j < 4; ++j) {
            float4 xv = ok ? *(const float4*)(xp + j * 4)
                           : make_float4(0.f, 0.f, 0.f, 0.f);
            int k = kbase + j * 4;
            xs_t[(k + 0) * 36 + row] = xv.x;
            xs_t[(k + 1) * 36 + row] = xv.y;
            xs_t[(k + 2) * 36 + row] = xv.z;
            xs_t[(k + 3) * 36 + row] = xv.w;
        }
    }
    __syncthreads();

    // ---- compute 4 rows x 4 cols per thread ----
    int c4 = (tid & 31) << 2;
    int r4 = (tid >> 5) << 2;

    float4 acc0 = make_float4(0.f, 0.f, 0.f, 0.f);
    float4 acc1 = make_float4(0.f, 0.f, 0.f, 0.f);
    float4 acc2 = make_float4(0.f, 0.f, 0.f, 0.f);
    float4 acc3 = make_float4(0.f, 0.f, 0.f, 0.f);

#pragma unroll 8
    for (int k = 0; k < 128; ++k) {
        float4 xv = *(const float4*)(xs_t + k * 36 + r4);
        float4 wv = *(const float4*)(W + k * IN_F + c4);
        acc0.x += xv.x * wv.x; acc0.y += xv.x * wv.y; acc0.z += xv.x * wv.z; acc0.w += xv.x * wv.w;
        acc1.x += xv.y * wv.x; acc1.y += xv.y * wv.y; acc1.z += xv.y * wv.z; acc1.w += xv.y * wv.w;
        acc2.x += xv.z * wv.x; acc2.y += xv.z * wv.y; acc2.z += xv.z * wv.z; acc2.w += xv.z * wv.w;
        acc3.x += xv.w * wv.x; acc3.y += xv.w * wv.y; acc3.z += xv.w * wv.z; acc3.w += xv.w * wv.w;
    }

    int grow = blockIdx.x * 32 + r4;

    // ---- store h as fp16 ----
#pragma unroll
    for (int r = 0; r < 4; ++r) {
        float4 a = (r == 0) ? acc0 : (r == 1) ? acc1 : (r == 2) ? acc2 : acc3;
        if (grow + r < n_nodes) {
            __half2 pa = __floats2half2_rn(a.x, a.y);
            __half2 pb = __floats2half2_rn(a.z, a.w);
            __half* hp = h16 + (((unsigned)(grow + r)) << 7) + c4;
            *(__half2*)(hp + 0) = pa;
            *(__half2*)(hp + 2) = pb;
        }
    }

    // ---- fused attention halves (full fp32 precision) ----
    int hh = c4 >> 5;          // head of this thread's 4 cols
    int cw = c4 & 31;          // within-head col
    float4 asv = *(const float4*)(att_src + (hh << 5) + cw);
    float4 adv = *(const float4*)(att_dst + (hh << 5) + cw);

    float ps0 = acc0.x*asv.x + acc0.y*asv.y + acc0.z*asv.z + acc0.w*asv.w;
    float ps1 = acc1.x*asv.x + acc1.y*asv.y + acc1.z*asv.z + acc1.w*asv.w;
    float ps2 = acc2.x*asv.x + acc2.y*asv.y + acc2.z*asv.z + acc2.w*asv.w;
    float ps3 = acc3.x*asv.x + acc3.y*asv.y + acc3.z*asv.z + acc3.w*asv.w;
    float pd0 = acc0.x*adv.x + acc0.y*adv.y + acc0.z*adv.z + acc0.w*adv.w;
    float pd1 = acc1.x*adv.x + acc1.y*adv.y + acc1.z*adv.z + acc1.w*adv.w;
    float pd2 = acc2.x*adv.x + acc2.y*adv.y + acc2.z*adv.z + acc2.w*adv.w;
    float pd3 = acc3.x*adv.x + acc3.y*adv.y + acc3.z*adv.z + acc3.w*adv.w;

    // segmented reduce over the 8 lanes sharing (row-quad, head)
#pragma unroll
    for (int m = 1; m <= 4; m <<= 1) {
        ps0 += __shfl_xor(ps0, m); pd0 += __shfl_xor(pd0, m);
        ps1 += __shfl_xor(ps1, m); pd1 += __shfl_xor(pd1, m);
        ps2 += __shfl_xor(ps2, m); pd2 += __shfl_xor(pd2, m);
        ps3 += __shfl_xor(ps3, m); pd3 += __shfl_xor(pd3, m);
    }

    if ((tid & 7) == 0) {
#pragma unroll
        for (int r = 0; r < 4; ++r) {
            float ps = (r == 0) ? ps0 : (r == 1) ? ps1 : (r == 2) ? ps2 : ps3;
            float pd = (r == 0) ? pd0 : (r == 1) ? pd1 : (r == 2) ? pd2 : pd3;
            int n = grow + r;
            if (n < n_nodes) {
                s_src[((unsigned)n << 2) + hh] = ps;
                s_dst[((unsigned)n << 2) + hh] = pd;
            }
        }
    }
}

// ---------------------------------------------------------------------------
// 3-phase exclusive scan cascade (multi-block, each dispatch ~5-10us).
// ---------------------------------------------------------------------------
__global__ __launch_bounds__(256) void scan1_kernel(const int* __restrict__ deg,
                                                    int* __restrict__ blksum, int N) {
    __shared__ int s[256];
    int base = blockIdx.x * 1024 + threadIdx.x * 4;
    int sum = 0;
#pragma unroll
    for (int j = 0; j < 4; ++j) { int i = base + j; if (i < N) sum += deg[i]; }
    s[threadIdx.x] = sum;
    __syncthreads();
    for (int off = 128; off > 0; off >>= 1) {
        if (threadIdx.x < off) s[threadIdx.x] += s[threadIdx.x + off];
        __syncthreads();
    }
    if (threadIdx.x == 0) blksum[blockIdx.x] = s[0];
}

__global__ __launch_bounds__(256) void scan2_kernel(const int* __restrict__ blksum,
                                                    int* __restrict__ blkoff, int nblk) {
    __shared__ int s[256];
    int t = threadIdx.x;
    int v = (t < nblk) ? blksum[t] : 0;
    s[t] = v;
    __syncthreads();
    for (int off = 1; off < 256; off <<= 1) {
        int add = (t >= off) ? s[t - off] : 0;
        __syncthreads();
        s[t] += add;
        __syncthreads();
    }
    if (t < nblk) blkoff[t] = s[t] - v;   // exclusive
}

__global__ __launch_bounds__(256) void scan3_kernel(int* __restrict__ deg,
                                                    const int* __restrict__ blkoff,
                                                    int* __restrict__ rowptr, int N) {
    __shared__ int s[256];
    int t = threadIdx.x;
    int base = blockIdx.x * 1024 + t * 4;
    int d[4];
    int loc = 0;
#pragma unroll
    for (int j = 0; j < 4; ++j) { int i = base + j; d[j] = (i < N) ? deg[i] : 0; loc += d[j]; }
    s[t] = loc;
    __syncthreads();
    for (int off = 1; off < 256; off <<= 1) {
        int add = (t >= off) ? s[t - off] : 0;
        __syncthreads();
        s[t] += add;
        __syncthreads();
    }
    int run = s[t] - loc + blkoff[blockIdx.x];
#pragma unroll
    for (int j = 0; j < 4; ++j) {
        int i = base + j;
        if (i < N) {
            rowptr[i] = run;
            deg[i]    = run;        // reuse deg as the scatter cursor
            run += d[j];
            if (i == N - 1) rowptr[N] = run;
        }
    }
}

// ---------------------------------------------------------------------------
// K4: pure counting-sort scatter of src ids (pexp path deleted — the
// softmax numerator is recomputed in the aggregate from L2-resident s_*).
// ---------------------------------------------------------------------------
__global__ __launch_bounds__(256) void fill_kernel(const int* __restrict__ ei,
                                                   int* __restrict__ cursor,
                                                   int* __restrict__ esrc, int E) {
    int e = blockIdx.x * 256 + threadIdx.x;
    if (e >= E) return;
    int s = ei[e], d = ei[E + e];
    int pos = atomicAdd(&cursor[d], 1);
    esrc[pos] = s;
}

// ---------------------------------------------------------------------------
// K5: gather-reduce aggregate. Persistent grid-stride waves; lane owns 2
// features. Per edge: s_src gather (4B, L2-resident 1.6MB) + inline
// leaky/exp + fp16 h row gather. No pexp stream.
// ---------------------------------------------------------------------------
#define AGG_BLOCKS 2048
__global__ __launch_bounds__(256) void aggregate_kernel(const int* __restrict__ rowptr,
                                                        const int* __restrict__ esrc,
                                                        const __half* __restrict__ h16,
                                                        const float* __restrict__ s_src,
                                                        const float* __restrict__ s_dst,
                                                        const float* __restrict__ bias,
                                                        float* __restrict__ out,
                                                        int N) {
    int lane = threadIdx.x & 63;
    int gw   = blockIdx.x * 4 + (threadIdx.x >> 6);   // global wave id
    const int NW = AGG_BLOCKS * 4;

    unsigned f  = (unsigned)lane * 2u;     // this lane's 2 features
    int      hh = lane >> 4;               // head

    float bx = bias[f], by = bias[f + 1];  // node-invariant

    for (int n = gw; n < N; n += NW) {
        float sdst = s_dst[((unsigned)n << 2) + hh];

        // self-loop message
        float e0 = s_src[((unsigned)n << 2) + hh] + sdst;
        e0 = e0 > 0.f ? e0 : NEG_SLOPE * e0;
        float p0 = __expf(e0);
        float2 hv = __half22float2(*(const __half2*)(h16 + (((unsigned)n << 7) | f)));
        float accx = p0 * hv.x, accy = p0 * hv.y, den = p0;

        int k0 = rowptr[n], k1 = rowptr[n + 1];
        for (int base = k0; base < k1; base += 64) {
            int cnt = k1 - base; if (cnt > 64) cnt = 64;
            int msrc = (lane < cnt) ? esrc[base + lane] : 0;
#pragma unroll 8
            for (int j = 0; j < cnt; ++j) {
                int src = __builtin_amdgcn_readlane(msrc, j);   // j wave-uniform -> SGPR
                float ss = s_src[((unsigned)src << 2) | (unsigned)hh];
                float v  = ss + sdst;
                v = v > 0.f ? v : NEG_SLOPE * v;
                float pp = __expf(v);
                float2 hs = __half22float2(*(const __half2*)(h16 + (((unsigned)src << 7) | f)));
                accx += pp * hs.x;
                accy += pp * hs.y;
                den  += pp;
            }
        }

        float inv = 1.f / (den + 1e-16f);
        float2 o;
        o.x = accx * inv + bx;
        o.y = accy * inv + by;
        *(float2*)(out + (((unsigned)n << 7) | f)) = o;
    }
}

// ---------------------------------------------------------------------------
extern "C" void kernel_launch(void* const* d_in, const int* in_sizes, int n_in,
                              void* d_out, int out_size, void* d_ws, size_t ws_size,
                              hipStream_t stream) {
    const float* x       = (const float*)d_in[0];
    const int*   ei      = (const int*)d_in[1];   // harness stages integers as int32
    const float* W       = (const float*)d_in[2];
    const float* att_src = (const float*)d_in[3];
    const float* att_dst = (const float*)d_in[4];
    const float* bias    = (const float*)d_in[5];
    float*       out     = (float*)d_out;

    const int N = in_sizes[0] / IN_F;   // 100000
    const int E = in_sizes[1] / 2;      // 1600000

    // workspace layout (~34 MB)
    char*   wsp    = (char*)d_ws;
    __half* h16    = (__half*)wsp;                    wsp += (size_t)N * IN_F * 2;
    float*  s_src  = (float*)wsp;                     wsp += (size_t)N * HEADS * 4;
    float*  s_dst  = (float*)wsp;                     wsp += (size_t)N * HEADS * 4;
    int*    esrc   = (int*)wsp;                       wsp += (size_t)E * 4;
    int*    deg    = (int*)wsp;                       wsp += (size_t)N * 4;
    int*    rowptr = (int*)wsp;                       wsp += (size_t)(N + 1) * 4;
    int*    blksum = (int*)wsp;                       wsp += 256 * 4;
    int*    blkoff = (int*)wsp;

    const int nblk_scan = (N + 1023) / 1024;          // 98 <= 256

    // 6 dispatches + 1 memset: memset(deg), gemm(+count), scan1/2/3, fill, aggregate
    hipMemsetAsync(deg, 0, (size_t)N * 4, stream);
    gemm_fused_kernel<<<(N + 31) / 32, 256, 0, stream>>>(x, W, att_src, att_dst,
                                                         ei + E, h16, s_src, s_dst,
                                                         deg, N, E);
    scan1_kernel<<<nblk_scan, 256, 0, stream>>>(deg, blksum, N);
    scan2_kernel<<<1, 256, 0, stream>>>(blksum, blkoff, nblk_scan);
    scan3_kernel<<<nblk_scan, 256, 0, stream>>>(deg, blkoff, rowptr, N);
    fill_kernel<<<(E + 255) / 256, 256, 0, stream>>>(ei, deg, esrc, E);
    aggregate_kernel<<<AGG_BLOCKS, 256, 0, stream>>>(rowptr, esrc, h16,
                                                     s_src, s_dst, bias, out, N);
}